// Round 11
// baseline (1734.589 us; speedup 1.0000x reference)
//
#include <hip/hip_runtime.h>
#include <hip/hip_cooperative_groups.h>
#include <math.h>

namespace cg = cooperative_groups;

#define B 2048
#define H 1024
#define HH (1024 * 1024)

typedef __attribute__((ext_vector_type(8))) short bf16x8;
typedef __attribute__((ext_vector_type(4))) float floatx4;

// ---------------- bf16 split helpers (RNE) ----------------
__device__ __forceinline__ short bf16_rne(float x) {
    unsigned int b = __float_as_uint(x);
    unsigned int r = (b + 0x7fffu + ((b >> 16) & 1u)) >> 16;
    return (short)r;
}
__device__ __forceinline__ float bf16_f(short h) {
    return __uint_as_float(((unsigned int)(unsigned short)h) << 16);
}
__device__ __forceinline__ void split2(float x, short& h, short& l) {
    h = bf16_rne(x);
    l = bf16_rne(x - bf16_f(h));
}
__device__ __forceinline__ float ld3(const float* f, const short* h, const short* l, size_t i) {
    if (f) return f[i];
    return bf16_f(h[i]) + bf16_f(l[i]);
}

// async global->LDS, 16B per lane; LDS dest = wave-uniform base + lane*16
__device__ __forceinline__ void gl16(const void* g, void* l) {
    __builtin_amdgcn_global_load_lds(
        (const __attribute__((address_space(1))) void*)g,
        (__attribute__((address_space(3))) void*)l, 16, 0, 0);
}

// ---------------------------------------------------------------------------
// One 128x128 GEMM tile: C[m0.., n0..] = A * W^T-plane. Split-bf16 3-term
// product (Ah*Bh + Ah*Bl + Al*Bh), BK=32, 16x16x32 MFMA 4x4/wave, dbuf LDS,
// chunk-XOR swizzle (0 bank conflicts). Optional fused e0 sigmoid epilogue.
// ---------------------------------------------------------------------------
struct Job {
    const short* ah; const short* al;   // A hi/lo, [2048][1024]
    const short* wh; const short* wl;   // W^T hi/lo plane, [1024][1024]
    float* c;                           // output plane base (or null if ep)
    long ldc;                           // C row stride (floats)
    const float* epAdd;                 // e0: fp32 addend, stride 3072
    const float* epBias;                // e0: bias slice
    short* epH; short* epL;             // e0: bf16 pair out, stride 1024
};

__device__ __forceinline__ void gemm_tile(const Job& jb, int mi, int ni,
                                          short (*lds)[4][4096])
{
    const int tid = threadIdx.x;
    const int w = tid >> 6, lane = tid & 63;
    const int wm = w >> 1, wn = w & 1;
    const int m0 = mi * 128, n0 = ni * 128;

    // staging: chunk cid = j*256+tid; row=cid>>2; src k-chunk = (cid&3)^((cid>>3)&3)
    const int cid0 = tid, cid1 = 256 + tid;
    const int r0 = cid0 >> 2, g0 = (((cid0 & 3) ^ ((cid0 >> 3) & 3)) << 3);
    const int r1 = cid1 >> 2, g1 = (((cid1 & 3) ^ ((cid1 >> 3) & 3)) << 3);

    const short* p0[4] = { jb.ah + (size_t)(m0 + r0) * H + g0,
                           jb.al + (size_t)(m0 + r0) * H + g0,
                           jb.wh + (size_t)(n0 + r0) * H + g0,
                           jb.wl + (size_t)(n0 + r0) * H + g0 };
    const short* p1[4] = { jb.ah + (size_t)(m0 + r1) * H + g1,
                           jb.al + (size_t)(m0 + r1) * H + g1,
                           jb.wh + (size_t)(n0 + r1) * H + g1,
                           jb.wl + (size_t)(n0 + r1) * H + g1 };

    const int fr = lane & 15, kc = lane >> 4;
    int aoff[4], boff[4];
#pragma unroll
    for (int t = 0; t < 4; t++) {
        int ar = wm * 64 + t * 16 + fr;
        aoff[t] = ar * 32 + ((kc ^ ((ar >> 1) & 3)) << 3);
        int br = wn * 64 + t * 16 + fr;
        boff[t] = br * 32 + ((kc ^ ((br >> 1) & 3)) << 3);
    }

    floatx4 acc[4][4];
#pragma unroll
    for (int i = 0; i < 4; i++)
#pragma unroll
        for (int j = 0; j < 4; j++) acc[i][j] = (floatx4)0.f;

#define ISSUE8(P)                                                        \
    do {                                                                 \
        _Pragma("unroll")                                                \
        for (int o = 0; o < 4; o++) {                                    \
            gl16(p0[o], &lds[P][o][w * 512]);                            \
            gl16(p1[o], &lds[P][o][2048 + w * 512]);                     \
            p0[o] += 32; p1[o] += 32;                                    \
        }                                                                \
    } while (0)

#define COMPUTE(P)                                                       \
    do {                                                                 \
        bf16x8 fah[4], fal[4], fbh[4], fbl[4];                           \
        _Pragma("unroll")                                                \
        for (int t = 0; t < 4; t++) {                                    \
            fah[t] = *(const bf16x8*)&lds[P][0][aoff[t]];                \
            fal[t] = *(const bf16x8*)&lds[P][1][aoff[t]];                \
            fbh[t] = *(const bf16x8*)&lds[P][2][boff[t]];                \
            fbl[t] = *(const bf16x8*)&lds[P][3][boff[t]];                \
        }                                                                \
        _Pragma("unroll")                                                \
        for (int mt = 0; mt < 4; mt++)                                   \
            _Pragma("unroll")                                            \
            for (int nt = 0; nt < 4; nt++) {                             \
                acc[mt][nt] = __builtin_amdgcn_mfma_f32_16x16x32_bf16(fah[mt], fbh[nt], acc[mt][nt], 0, 0, 0); \
                acc[mt][nt] = __builtin_amdgcn_mfma_f32_16x16x32_bf16(fah[mt], fbl[nt], acc[mt][nt], 0, 0, 0); \
                acc[mt][nt] = __builtin_amdgcn_mfma_f32_16x16x32_bf16(fal[mt], fbh[nt], acc[mt][nt], 0, 0, 0); \
            }                                                            \
    } while (0)

    ISSUE8(0);
    for (int ks = 0; ks < 32; ks += 2) {
        __syncthreads();
        ISSUE8(1);
        COMPUTE(0);
        __syncthreads();
        if (ks + 2 < 32) ISSUE8(0);
        COMPUTE(1);
    }
#undef ISSUE8
#undef COMPUTE

    // C/D layout: col = lane&15, row = (lane>>4)*4 + reg
    const int cr = (lane >> 4) * 4, cc = lane & 15;
    if (jb.epH) {
#pragma unroll
        for (int mt = 0; mt < 4; mt++)
#pragma unroll
            for (int nt = 0; nt < 4; nt++) {
                const int gr = m0 + wm * 64 + mt * 16 + cr;
                const int gc = n0 + wn * 64 + nt * 16 + cc;
                const float bv = jb.epBias[gc];
#pragma unroll
                for (int i = 0; i < 4; i++) {
                    float v = acc[mt][nt][i] + jb.epAdd[(size_t)(gr + i) * 3072 + gc] + bv;
                    float sg = 1.f / (1.f + expf(-v));
                    short hh, ll; split2(sg, hh, ll);
                    jb.epH[(size_t)(gr + i) * 1024 + gc] = hh;
                    jb.epL[(size_t)(gr + i) * 1024 + gc] = ll;
                }
            }
    } else {
#pragma unroll
        for (int mt = 0; mt < 4; mt++)
#pragma unroll
            for (int nt = 0; nt < 4; nt++) {
                float* Cp = jb.c + (size_t)(m0 + wm * 64 + mt * 16 + cr) * jb.ldc
                                 + n0 + wn * 64 + nt * 16 + cc;
#pragma unroll
                for (int i = 0; i < 4; i++) Cp[(size_t)i * jb.ldc] = acc[mt][nt][i];
            }
    }
}

// ---------------------------------------------------------------------------
// Params for the whole cell
// ---------------------------------------------------------------------------
struct MegaParams {
    Job g1[4], g2[4], g3[6], g4[8], g5[4], g6[3];
    const float *xs, *hs, *L, *R, *bias, *w;
    short *p1h, *p1l, *p2h, *p2l, *p3h, *p3l, *p4h, *p4l;
    short *lth, *ltl, *rth, *rtl;
    float *fA, *fB, *fC, *fD, *out, *G;
    int* ctr;                           // 16 ints in ws (stage tile counters)
};

// wsplit tile t in [0,6144): zz=t/1024, ky=(t%1024)/32, nx=t%32
__device__ __forceinline__ void wsplit_tile(int t, const MegaParams& mp,
                                            float (*tb)[33])
{
    const int zz = t >> 10;
    const int rest = t & 1023;
    const int k0 = (rest >> 5) << 5, n0 = (rest & 31) << 5;
    const float* W = (zz < 3) ? mp.L : mp.R;
    short* Oh = (zz < 3) ? mp.lth : mp.rth;
    short* Ol = (zz < 3) ? mp.ltl : mp.rtl;
    const int z = (zz < 3) ? zz : zz - 3;
    const int tx = threadIdx.x & 31, ty = threadIdx.x >> 5;
    const float* src = W + (size_t)z * HH;
#pragma unroll
    for (int j = 0; j < 4; j++) {
        int r = ty + j * 8;
        tb[r][tx] = src[(size_t)(k0 + r) * 1024 + n0 + tx];
    }
    __syncthreads();
    short* oh = Oh + (size_t)z * HH;
    short* ol = Ol + (size_t)z * HH;
#pragma unroll
    for (int j = 0; j < 4; j++) {
        int n = ty + j * 8;
        float v = tb[tx][n];
        short hh, ll; split2(v, hh, ll);
        oh[(size_t)(n0 + n) * 1024 + k0 + tx] = hh;
        ol[(size_t)(n0 + n) * 1024 + k0 + tx] = ll;
    }
    __syncthreads();
}

__device__ __forceinline__ float wave_red(float v)
{
#pragma unroll
    for (int o = 32; o; o >>= 1) v += __shfl_down(v, o, 64);
    return v;
}

// ---------------------------------------------------------------------------
// mix3 row b: rh = mix(hsL*rR+b) G3 ; omz = mix(1-(z1R+b)) G5 ;
//             z2h = mix(hsL*z1R+b) G7. cand3 analytic from hs, z1, r pairs.
// ---------------------------------------------------------------------------
__device__ void mix3_row(const MegaParams& mp, int b,
                         float (*red)[4], float* probs)
{
    const int tid = threadIdx.x;
    const size_t base = (size_t)b * 3072;
    const size_t vbase = (size_t)b * 1024;
    float v[3][4][4], sc[3][4];
#pragma unroll
    for (int m = 0; m < 3; m++)
#pragma unroll
        for (int k = 0; k < 4; k++) sc[m][k] = 0.f;
#pragma unroll
    for (int k = 0; k < 4; k++)
#pragma unroll
        for (int i = 0; i < 4; i++) {
            int h = tid + i * 256;
            float hl, rr, zr;
            if (k < 3) {
                hl = mp.fB[base + k * 1024 + h];
                rr = mp.fC[base + k * 1024 + h];
                zr = mp.fD[base + k * 1024 + h];
            } else {
                hl = mp.hs[vbase + h];
                rr = bf16_f(mp.p4h[vbase + h]) + bf16_f(mp.p4l[vbase + h]);
                zr = bf16_f(mp.p3h[vbase + h]) + bf16_f(mp.p3l[vbase + h]);
            }
            float bk = mp.bias[k * 1024 + h];
            float wv = mp.w[h];
            float a = fmaf(hl, rr, bk);
            float c = 1.0f - (zr + bk);
            float d = fmaf(hl, zr, bk);
            v[0][k][i] = a; v[1][k][i] = c; v[2][k][i] = d;
            sc[0][k] = fmaf(a, wv, sc[0][k]);
            sc[1][k] = fmaf(c, wv, sc[1][k]);
            sc[2][k] = fmaf(d, wv, sc[2][k]);
        }
    const int wid = tid >> 6, lane = tid & 63;
#pragma unroll
    for (int m = 0; m < 3; m++)
#pragma unroll
        for (int k = 0; k < 4; k++) {
            float s = wave_red(sc[m][k]);
            if (lane == 0) red[m * 4 + k][wid] = s;
        }
    __syncthreads();
    if (tid < 3) {
        int m = tid;
        float s[4];
#pragma unroll
        for (int k = 0; k < 4; k++)
            s[k] = red[m * 4 + k][0] + red[m * 4 + k][1] + red[m * 4 + k][2] + red[m * 4 + k][3];
        int am = 0; float mx = s[0];
#pragma unroll
        for (int k = 1; k < 4; k++) if (s[k] > mx) { mx = s[k]; am = k; }
        float e[4], tot = 0.f;
#pragma unroll
        for (int k = 0; k < 4; k++) { e[k] = expf(s[k] - mx); tot += e[k]; }
#pragma unroll
        for (int k = 0; k < 4; k++) probs[m * 4 + k] = e[k] / tot;
        int gcol = (m == 0) ? 3 : (m == 1) ? 5 : 7;
        mp.G[(size_t)b * 9 + gcol] = (float)am;
    }
    __syncthreads();
    float p[3][4];
#pragma unroll
    for (int m = 0; m < 3; m++)
#pragma unroll
        for (int k = 0; k < 4; k++) p[m][k] = probs[m * 4 + k];
#pragma unroll
    for (int i = 0; i < 4; i++) {
        int h = tid + i * 256;
        float o0 = 0, o1 = 0, o2 = 0;
#pragma unroll
        for (int k = 0; k < 4; k++) {
            o0 = fmaf(p[0][k], v[0][k][i], o0);
            o1 = fmaf(p[1][k], v[1][k][i], o1);
            o2 = fmaf(p[2][k], v[2][k][i], o2);
        }
        short hh, ll;
        split2(o0, hh, ll); mp.p1h[vbase + h] = hh; mp.p1l[vbase + h] = ll;
        split2(o1, hh, ll); mp.p2h[vbase + h] = hh; mp.p2l[vbase + h] = ll;
        split2(o2, hh, ll); mp.p3h[vbase + h] = hh; mp.p3l[vbase + h] = ll;
    }
    __syncthreads();   // safe reuse of red/probs by next row
}

// ---------------------------------------------------------------------------
// generic mix row. OP 0: p*q+b ; 1: tanh(p+q+b) ; 2: p+q+b.
// ---------------------------------------------------------------------------
template <int OP>
__device__ void mix_row(int b,
    const float* P, const float* Q,
    const float* a3f, const short* a3h, const short* a3l,
    const float* b3f, const short* b3h, const short* b3l,
    const float* bias, const float* wsc,
    float* of, short* oh, short* ol,
    float* G, int gcol,
    float (*red)[4], float* probs)
{
    const int tid = threadIdx.x;
    const size_t base = (size_t)b * 3072;
    const size_t vbase = (size_t)b * 1024;
    float v[4][4];
    float sc[4] = {0.f, 0.f, 0.f, 0.f};
#pragma unroll
    for (int k = 0; k < 4; k++)
#pragma unroll
        for (int i = 0; i < 4; i++) {
            int h = tid + i * 256;
            float pp, qq;
            if (k < 3) {
                pp = P[base + k * 1024 + h];
                qq = Q[base + k * 1024 + h];
            } else {
                pp = ld3(a3f, a3h, a3l, vbase + h);
                qq = ld3(b3f, b3h, b3l, vbase + h);
            }
            float bk = bias[k * 1024 + h];
            float val;
            if (OP == 0)      val = fmaf(pp, qq, bk);
            else if (OP == 1) val = tanhf(pp + qq + bk);
            else              val = pp + qq + bk;
            v[k][i] = val;
            sc[k] = fmaf(val, wsc[h], sc[k]);
        }
    const int wid = tid >> 6, lane = tid & 63;
#pragma unroll
    for (int k = 0; k < 4; k++) {
        float s = wave_red(sc[k]);
        if (lane == 0) red[k][wid] = s;
    }
    __syncthreads();
    if (tid == 0) {
        float s[4];
#pragma unroll
        for (int k = 0; k < 4; k++)
            s[k] = red[k][0] + red[k][1] + red[k][2] + red[k][3];
        int am = 0; float mx = s[0];
#pragma unroll
        for (int k = 1; k < 4; k++) if (s[k] > mx) { mx = s[k]; am = k; }
        float e[4], tot = 0.f;
#pragma unroll
        for (int k = 0; k < 4; k++) { e[k] = expf(s[k] - mx); tot += e[k]; }
#pragma unroll
        for (int k = 0; k < 4; k++) probs[k] = e[k] / tot;
        G[(size_t)b * 9 + gcol] = (float)am;
    }
    __syncthreads();
    float p0 = probs[0], p1 = probs[1], p2 = probs[2], p3 = probs[3];
#pragma unroll
    for (int i = 0; i < 4; i++) {
        int h = tid + i * 256;
        float o = p0 * v[0][i];
        o = fmaf(p1, v[1][i], o);
        o = fmaf(p2, v[2][i], o);
        o = fmaf(p3, v[3][i], o);
        if (oh) {
            short hh, ll; split2(o, hh, ll);
            oh[vbase + h] = hh;
            ol[vbase + h] = ll;
        } else {
            of[vbase + h] = o;
        }
    }
    __syncthreads();
}

// mix stage wrappers (shared by mega + fallback)
__device__ __forceinline__ void mixE2_row(const MegaParams& mp, int b,
                                          float (*red)[4], float* probs) {
    mix_row<1>(b, mp.fA, mp.fB, mp.xs, nullptr, nullptr,
               nullptr, mp.p1h, mp.p1l, mp.bias, mp.w,
               nullptr, mp.p4h, mp.p4l, mp.G, 4, red, probs);
}
__device__ __forceinline__ void mixE3_row(const MegaParams& mp, int b,
                                          float (*red)[4], float* probs) {
    mix_row<0>(b, mp.fA, mp.fC, nullptr, mp.p4h, mp.p4l,
               nullptr, mp.p2h, mp.p2l, mp.bias, mp.w,
               nullptr, mp.p1h, mp.p1l, mp.G, 6, red, probs);
}
__device__ __forceinline__ void mixE4_row(const MegaParams& mp, int b,
                                          float (*red)[4], float* probs) {
    mix_row<2>(b, mp.fB, mp.fD, nullptr, mp.p1h, mp.p1l,
               nullptr, mp.p3h, mp.p3l, mp.bias, mp.w,
               mp.out, nullptr, nullptr, mp.G, 8, red, probs);
}

// dynamic tile-stealing GEMM stage (tile decode: z = t>>7, mi=(t&127)>>3, ni=t&7)
__device__ void gemm_stage(const Job* jobs, int ntiles, int* ctr,
                           short (*lds)[4][4096])
{
    __shared__ int st;
    for (;;) {
        if (threadIdx.x == 0) st = atomicAdd(ctr, 1);
        __syncthreads();
        int t = st;
        if (t >= ntiles) break;
        const int r = t & 127;
        gemm_tile(jobs[t >> 7], r >> 3, r & 7, lds);
    }
}

// ---------------------------------------------------------------------------
// Cooperative mega-kernel: all stages, grid = 512 blocks (2/CU co-resident).
// ---------------------------------------------------------------------------
__global__ __launch_bounds__(256, 2) void mega_kernel(MegaParams mp)
{
    __shared__ short lds[2][4][4096];   // 64 KB (gemm dbuf; aliased by wsplit)
    __shared__ float red[12][4];
    __shared__ float probs[12];
    cg::grid_group grid = cg::this_grid();
    const int tid = threadIdx.x;

    // ---- stage 0: counters, G zero, conv, wsplit ----
    if (blockIdx.x == 0 && tid < 16) mp.ctr[tid] = 0;
    for (size_t i = (size_t)blockIdx.x * 256 + tid; i < (size_t)B * H; i += 512 * 256) {
        if (i < (size_t)B * 9) mp.G[i] = 0.f;
        short a, b2;
        split2(mp.xs[i], a, b2); mp.p1h[i] = a; mp.p1l[i] = b2;
        split2(mp.hs[i], a, b2); mp.p2h[i] = a; mp.p2l[i] = b2;
    }
    {
        float (*tb)[33] = (float(*)[33])lds;
        for (int t = blockIdx.x; t < 6144; t += 512) wsplit_tile(t, mp, tb);
    }
    __threadfence(); grid.sync();

    gemm_stage(mp.g1, 4 * 128, mp.ctr + 0, lds);  __threadfence(); grid.sync();
    gemm_stage(mp.g2, 4 * 128, mp.ctr + 1, lds);  __threadfence(); grid.sync();
    gemm_stage(mp.g3, 6 * 128, mp.ctr + 2, lds);  __threadfence(); grid.sync();
    for (int b = blockIdx.x; b < B; b += 512) mix3_row(mp, b, red, probs);
    __threadfence(); grid.sync();
    gemm_stage(mp.g4, 8 * 128, mp.ctr + 3, lds);  __threadfence(); grid.sync();
    for (int b = blockIdx.x; b < B; b += 512) mixE2_row(mp, b, red, probs);
    __threadfence(); grid.sync();
    gemm_stage(mp.g5, 4 * 128, mp.ctr + 4, lds);  __threadfence(); grid.sync();
    for (int b = blockIdx.x; b < B; b += 512) mixE3_row(mp, b, red, probs);
    __threadfence(); grid.sync();
    gemm_stage(mp.g6, 3 * 128, mp.ctr + 5, lds);  __threadfence(); grid.sync();
    for (int b = blockIdx.x; b < B; b += 512) mixE4_row(mp, b, red, probs);
}

// ---------------------------------------------------------------------------
// Fallback (non-cooperative) kernels — same device code, dispatch-per-stage.
// ---------------------------------------------------------------------------
struct Jobs8 { Job j[8]; };

__global__ __launch_bounds__(256, 2) void gemm_fb(Jobs8 jobs)
{
    __shared__ short lds[2][4][4096];
    const int t = blockIdx.x, r = t & 127;
    gemm_tile(jobs.j[t >> 7], r >> 3, r & 7, lds);
}
__global__ __launch_bounds__(256) void conv_fb(MegaParams mp)
{
    size_t i = (size_t)blockIdx.x * 256 + threadIdx.x;
    if (i < (size_t)B * 9) mp.G[i] = 0.f;
    short a, b2;
    split2(mp.xs[i], a, b2); mp.p1h[i] = a; mp.p1l[i] = b2;
    split2(mp.hs[i], a, b2); mp.p2h[i] = a; mp.p2l[i] = b2;
}
__global__ __launch_bounds__(256) void wsplit_fb(MegaParams mp)
{
    __shared__ float tb[32][33];
    wsplit_tile(blockIdx.x, mp, tb);
}
__global__ __launch_bounds__(256) void mix3_fb(MegaParams mp)
{
    __shared__ float red[12][4]; __shared__ float probs[12];
    mix3_row(mp, blockIdx.x, red, probs);
}
template <int S>
__global__ __launch_bounds__(256) void mix_fb(MegaParams mp)
{
    __shared__ float red[12][4]; __shared__ float probs[12];
    if (S == 2) mixE2_row(mp, blockIdx.x, red, probs);
    else if (S == 3) mixE3_row(mp, blockIdx.x, red, probs);
    else mixE4_row(mp, blockIdx.x, red, probs);
}

// ---------------------------------------------------------------------------
extern "C" void kernel_launch(void* const* d_in, const int* in_sizes, int n_in,
                              void* d_out, int out_size, void* d_ws, size_t ws_size,
                              hipStream_t stream)
{
    const float* xs   = (const float*)d_in[0];
    const float* hs   = (const float*)d_in[1];
    const float* L    = (const float*)d_in[2];
    const float* R    = (const float*)d_in[3];
    const float* bias = (const float*)d_in[4];
    const float* w    = (const float*)d_in[5];

    float* out = (float*)d_out;
    float* G   = out + (size_t)B * H;

    // ws layout (153 MB): fA/fB/fC/fD 24 MB each; P1..P4 8 MB; weights 6 MB ea;
    // stage counters at +152 MB.
    char* wsb = (char*)d_ws;
    const size_t MB = 1024ull * 1024;
    float* fA = (float*)(wsb);
    float* fB = (float*)(wsb + 24 * MB);
    float* fC = (float*)(wsb + 48 * MB);
    float* fD = (float*)(wsb + 72 * MB);
    short* P1h = (short*)(wsb + 96 * MB);  short* P1l = P1h + 2 * MB;  // x -> rh -> zh
    short* P2h = (short*)(wsb + 104 * MB); short* P2l = P2h + 2 * MB;  // h -> omz
    short* P3h = (short*)(wsb + 112 * MB); short* P3l = P3h + 2 * MB;  // z1 -> z2h
    short* P4h = (short*)(wsb + 120 * MB); short* P4l = P4h + 2 * MB;  // r -> h_tilde
    short* Lth = (short*)(wsb + 128 * MB);
    short* Ltl = (short*)(wsb + 134 * MB);
    short* Rth = (short*)(wsb + 140 * MB);
    short* Rtl = (short*)(wsb + 146 * MB);
    int*   ctr = (int*)(wsb + 152 * MB);

    MegaParams mp{};
    mp.xs = xs; mp.hs = hs; mp.L = L; mp.R = R; mp.bias = bias; mp.w = w;
    mp.p1h = P1h; mp.p1l = P1l; mp.p2h = P2h; mp.p2l = P2l;
    mp.p3h = P3h; mp.p3l = P3l; mp.p4h = P4h; mp.p4l = P4l;
    mp.lth = Lth; mp.ltl = Ltl; mp.rth = Rth; mp.rtl = Rtl;
    mp.fA = fA; mp.fB = fB; mp.fC = fC; mp.fD = fD; mp.out = out; mp.G = G;
    mp.ctr = ctr;

    const Job JZ{};
    // G1: xsL0-2 -> fA, hsL0 -> fB p0
    for (int p = 0; p < 3; p++)
        mp.g1[p] = { P1h, P1l, Lth + (size_t)p * HH, Ltl + (size_t)p * HH, fA + p * 1024, 3072,
                     nullptr, nullptr, nullptr, nullptr };
    mp.g1[3] = { P2h, P2l, Lth, Ltl, fB, 3072, nullptr, nullptr, nullptr, nullptr };
    // G2: hsL1,2 -> fB p1,p2 ; hsR0 -> ep z1 (P3) ; hsR1 -> ep r (P4)
    for (int p = 1; p < 3; p++)
        mp.g2[p - 1] = { P2h, P2l, Lth + (size_t)p * HH, Ltl + (size_t)p * HH, fB + p * 1024, 3072,
                         nullptr, nullptr, nullptr, nullptr };
    mp.g2[2] = { P2h, P2l, Rth, Rtl, nullptr, 0, fA, bias, P3h, P3l };
    mp.g2[3] = { P2h, P2l, Rth + (size_t)HH, Rtl + (size_t)HH, nullptr, 0,
                 fA + 1024, bias + 1024, P4h, P4l };
    // G3: z1R0-2 -> fD, rR0-2 -> fC
    for (int p = 0; p < 3; p++) {
        mp.g3[p]     = { P3h, P3l, Rth + (size_t)p * HH, Rtl + (size_t)p * HH, fD + p * 1024, 3072,
                         nullptr, nullptr, nullptr, nullptr };
        mp.g3[3 + p] = { P4h, P4l, Rth + (size_t)p * HH, Rtl + (size_t)p * HH, fC + p * 1024, 3072,
                         nullptr, nullptr, nullptr, nullptr };
    }
    // G4: rhR0-2 -> fB, omzR0-2 -> fC, z2hR0 -> fD p0, z2hR1 -> fD p1
    for (int p = 0; p < 3; p++) {
        mp.g4[p]     = { P1h, P1l, Rth + (size_t)p * HH, Rtl + (size_t)p * HH, fB + p * 1024, 3072,
                         nullptr, nullptr, nullptr, nullptr };
        mp.g4[3 + p] = { P2h, P2l, Rth + (size_t)p * HH, Rtl + (size_t)p * HH, fC + p * 1024, 3072,
                         nullptr, nullptr, nullptr, nullptr };
    }
    mp.g4[6] = { P3h, P3l, Rth, Rtl, fD, 3072, nullptr, nullptr, nullptr, nullptr };
    mp.g4[7] = { P3h, P3l, Rth + (size_t)HH, Rtl + (size_t)HH, fD + 1024, 3072,
                 nullptr, nullptr, nullptr, nullptr };
    // G5: htL0-2 -> fA, z2hR2 -> fD p2
    for (int p = 0; p < 3; p++)
        mp.g5[p] = { P4h, P4l, Lth + (size_t)p * HH, Ltl + (size_t)p * HH, fA + p * 1024, 3072,
                     nullptr, nullptr, nullptr, nullptr };
    mp.g5[3] = { P3h, P3l, Rth + (size_t)2 * HH, Rtl + (size_t)2 * HH, fD + 2048, 3072,
                 nullptr, nullptr, nullptr, nullptr };
    // G6: zhL0-2 -> fB
    for (int p = 0; p < 3; p++)
        mp.g6[p] = { P1h, P1l, Lth + (size_t)p * HH, Ltl + (size_t)p * HH, fB + p * 1024, 3072,
                     nullptr, nullptr, nullptr, nullptr };
    (void)JZ;

    void* args[] = { &mp };
    hipError_t err = hipLaunchCooperativeKernel((void*)mega_kernel,
                                                dim3(512), dim3(256), args, 0, stream);
    if (err != hipSuccess) {
        (void)hipGetLastError();  // clear sticky error, fall back to dispatches
        dim3 blk(256);
        conv_fb<<<(B * H) / 256, blk, 0, stream>>>(mp);
        wsplit_fb<<<6144, blk, 0, stream>>>(mp);
        Jobs8 jb{};
        for (int i = 0; i < 4; i++) jb.j[i] = mp.g1[i];
        gemm_fb<<<512, blk, 0, stream>>>(jb);
        for (int i = 0; i < 4; i++) jb.j[i] = mp.g2[i];
        gemm_fb<<<512, blk, 0, stream>>>(jb);
        for (int i = 0; i < 6; i++) jb.j[i] = mp.g3[i];
        gemm_fb<<<768, blk, 0, stream>>>(jb);
        mix3_fb<<<B, blk, 0, stream>>>(mp);
        for (int i = 0; i < 8; i++) jb.j[i] = mp.g4[i];
        gemm_fb<<<1024, blk, 0, stream>>>(jb);
        mix_fb<2><<<B, blk, 0, stream>>>(mp);
        for (int i = 0; i < 4; i++) jb.j[i] = mp.g5[i];
        gemm_fb<<<512, blk, 0, stream>>>(jb);
        mix_fb<3><<<B, blk, 0, stream>>>(mp);
        for (int i = 0; i < 3; i++) jb.j[i] = mp.g6[i];
        gemm_fb<<<384, blk, 0, stream>>>(jb);
        mix_fb<4><<<B, blk, 0, stream>>>(mp);
    }
}